// Round 1
// baseline (891.213 us; speedup 1.0000x reference)
//
#include <hip/hip_runtime.h>
#include <stdint.h>
#include <stddef.h>

// MHA forward, MI355X. Pipeline:
//   proj:  Q/K/V = X @ W  (bf16 MFMA 16x16x32, f32 accum), Q pre-scaled 1/8
//   attn:  two-pass softmax per 64-row Q block; writes attn (537MB) once; PV via MFMA
//   out :  Ohead @ Wo + residual
// ws layout (bf16): Qh[2][16][2048][64] | Kh | Vh | Ohead[4096][1024]  = 32 MB

#define NH  16
#define DKH 64
#define DM  1024
#define BSZ 2
#define SEQ 2048
#define MTOT (BSZ*SEQ)   // 4096

typedef __attribute__((ext_vector_type(8))) __bf16 bf16x8;
typedef __attribute__((ext_vector_type(4))) float  f32x4;

static __device__ __forceinline__ unsigned short f2bf(float f) {
    unsigned u = __float_as_uint(f);
    u = (u + 0x7fffu + ((u >> 16) & 1u)) >> 16;   // round-to-nearest-even
    return (unsigned short)u;
}
static __device__ __forceinline__ bf16x8 ld_bf8(const unsigned short* p) {
    return *reinterpret_cast<const bf16x8*>(p);
}

// ---------------- projection GEMM: Y[b][h][l][d] = X(4096x1024) @ W(1024x1024) ----------------
__global__ __launch_bounds__(256) void proj_kernel(
    const float* __restrict__ qin, const float* __restrict__ kin, const float* __restrict__ vin,
    const float* __restrict__ Wq,  const float* __restrict__ Wk,  const float* __restrict__ Wv,
    unsigned short* __restrict__ Qh, unsigned short* __restrict__ Kh, unsigned short* __restrict__ Vh)
{
    const int z = blockIdx.z;
    const float* X = (z == 0) ? qin : (z == 1) ? kin : vin;
    const float* W = (z == 0) ? Wq  : (z == 1) ? Wk  : Wv;
    unsigned short* Y = (z == 0) ? Qh : (z == 1) ? Kh : Vh;
    const float scale = (z == 0) ? 0.125f : 1.0f;   // 1/sqrt(64) folded into Q

    __shared__ __align__(16) unsigned short Asm[64][40];   // A tile 64x32 bf16 (+pad)
    __shared__ __align__(16) unsigned short Bsm[64][40];   // W tile transposed: Bsm[n][k]

    const int t = threadIdx.x;
    const int lane = t & 63, wv = t >> 6;
    const int wrow = wv >> 1, wcol = wv & 1;
    const int l15 = lane & 15, lg = lane >> 4;
    const int m0 = blockIdx.x * 64, n0 = blockIdx.y * 64;

    f32x4 acc[2][2] = {};

    const int ar = t >> 2, ac0 = (t & 3) * 8;   // A staging: 64 rows x 32 cols
    const int br = t >> 3, bc0 = (t & 7) * 8;   // B staging: 32 k-rows x 64 n-cols

    for (int k0 = 0; k0 < DM; k0 += 32) {
        {   // stage A (f32 -> bf16)
            const float* sa = X + (size_t)(m0 + ar) * DM + (k0 + ac0);
            f32x4 a0 = *reinterpret_cast<const f32x4*>(sa);
            f32x4 a1 = *reinterpret_cast<const f32x4*>(sa + 4);
            unsigned short* dst = &Asm[ar][ac0];
            #pragma unroll
            for (int j = 0; j < 4; j++) dst[j]     = f2bf(a0[j]);
            #pragma unroll
            for (int j = 0; j < 4; j++) dst[4 + j] = f2bf(a1[j]);
        }
        {   // stage B transposed (f32 -> bf16): Bsm[n][k]
            const float* sb = W + (size_t)(k0 + br) * DM + (n0 + bc0);
            f32x4 b0 = *reinterpret_cast<const f32x4*>(sb);
            f32x4 b1 = *reinterpret_cast<const f32x4*>(sb + 4);
            #pragma unroll
            for (int j = 0; j < 4; j++) Bsm[bc0 + j][br]     = f2bf(b0[j]);
            #pragma unroll
            for (int j = 0; j < 4; j++) Bsm[bc0 + 4 + j][br] = f2bf(b1[j]);
        }
        __syncthreads();

        bf16x8 af0 = ld_bf8(&Asm[wrow*32 +      l15][lg*8]);
        bf16x8 af1 = ld_bf8(&Asm[wrow*32 + 16 + l15][lg*8]);
        bf16x8 bf0 = ld_bf8(&Bsm[wcol*32 +      l15][lg*8]);
        bf16x8 bf1 = ld_bf8(&Bsm[wcol*32 + 16 + l15][lg*8]);
        acc[0][0] = __builtin_amdgcn_mfma_f32_16x16x32_bf16(af0, bf0, acc[0][0], 0, 0, 0);
        acc[0][1] = __builtin_amdgcn_mfma_f32_16x16x32_bf16(af0, bf1, acc[0][1], 0, 0, 0);
        acc[1][0] = __builtin_amdgcn_mfma_f32_16x16x32_bf16(af1, bf0, acc[1][0], 0, 0, 0);
        acc[1][1] = __builtin_amdgcn_mfma_f32_16x16x32_bf16(af1, bf1, acc[1][1], 0, 0, 0);
        __syncthreads();
    }

    #pragma unroll
    for (int mi = 0; mi < 2; mi++)
        #pragma unroll
        for (int ni = 0; ni < 2; ni++)
            #pragma unroll
            for (int r = 0; r < 4; r++) {
                int gm = m0 + wrow*32 + mi*16 + lg*4 + r;      // b*2048 + l
                int gn = n0 + wcol*32 + ni*16 + l15;           // h*64 + d
                int bb = gm >> 11, ll = gm & (SEQ - 1);
                int hh = gn >> 6,  dd = gn & 63;
                Y[(((size_t)(bb*NH + hh))*SEQ + ll)*DKH + dd] = f2bf(acc[mi][ni][r] * scale);
            }
}

// ---------------- attention: per (b,h) x 64-row Q block ----------------
__global__ __launch_bounds__(256) void attn_kernel(
    const unsigned short* __restrict__ Qh, const unsigned short* __restrict__ Kh,
    const unsigned short* __restrict__ Vh, float* __restrict__ attn,
    unsigned short* __restrict__ Oh)
{
    const int bh = blockIdx.y;            // b*16 + h
    const int b  = bh >> 4, h = bh & 15;
    const int q0 = blockIdx.x * 64;
    const int t = threadIdx.x, lane = t & 63, wv = t >> 6;
    const int l15 = lane & 15, lg = lane >> 4;

    __shared__ __align__(16) unsigned short Ksm [64][72];   // [key][d]
    __shared__ __align__(16) unsigned short Vtsm[64][72];   // [dv][key] (transposed)
    __shared__ __align__(16) unsigned short Psm [64][72];   // [q][key] bf16 P

    const unsigned short* Kb = Kh + (size_t)bh * SEQ * DKH;
    const unsigned short* Vb = Vh + (size_t)bh * SEQ * DKH;
    const unsigned short* Qb = Qh + ((size_t)bh * SEQ + q0) * DKH;

    // Q fragments held in registers for this wave's 16 q-rows (Q pre-scaled by 1/8)
    bf16x8 qf0, qf1;
    {
        const unsigned short* qp = Qb + (size_t)(wv*16 + l15) * DKH + lg*8;
        qf0 = ld_bf8(qp);
        qf1 = ld_bf8(qp + 32);
    }

    float m_run[4], l_run[4];
    #pragma unroll
    for (int r = 0; r < 4; r++) { m_run[r] = -1e30f; l_run[r] = 0.f; }

    const int sk = t >> 2, sc0 = (t & 3) * 16;   // staging: row sk, 16 cols from sc0

    // ---------- pass 1: softmax stats (m, l) ----------
    for (int kt = 0; kt < SEQ; kt += 64) {
        const unsigned short* ks = Kb + (size_t)(kt + sk) * DKH + sc0;
        *reinterpret_cast<bf16x8*>(&Ksm[sk][sc0])     = ld_bf8(ks);
        *reinterpret_cast<bf16x8*>(&Ksm[sk][sc0 + 8]) = ld_bf8(ks + 8);
        __syncthreads();

        f32x4 s[4];
        #pragma unroll
        for (int ni = 0; ni < 4; ni++) {
            bf16x8 k0f = ld_bf8(&Ksm[ni*16 + l15][lg*8]);
            bf16x8 k1f = ld_bf8(&Ksm[ni*16 + l15][32 + lg*8]);
            f32x4 zz = {};
            zz    = __builtin_amdgcn_mfma_f32_16x16x32_bf16(qf0, k0f, zz, 0, 0, 0);
            s[ni] = __builtin_amdgcn_mfma_f32_16x16x32_bf16(qf1, k1f, zz, 0, 0, 0);
        }
        float tmax[4], tsum[4];
        #pragma unroll
        for (int r = 0; r < 4; r++)
            tmax[r] = fmaxf(fmaxf(s[0][r], s[1][r]), fmaxf(s[2][r], s[3][r]));
        #pragma unroll
        for (int off = 1; off < 16; off <<= 1)
            #pragma unroll
            for (int r = 0; r < 4; r++)
                tmax[r] = fmaxf(tmax[r], __shfl_xor(tmax[r], off, 64));
        #pragma unroll
        for (int r = 0; r < 4; r++) {
            float mnew = fmaxf(m_run[r], tmax[r]);
            float su = 0.f;
            #pragma unroll
            for (int ni = 0; ni < 4; ni++) su += __expf(s[ni][r] - mnew);
            tsum[r] = su;
            tmax[r] = mnew;          // reuse tmax as mnew
        }
        #pragma unroll
        for (int off = 1; off < 16; off <<= 1)
            #pragma unroll
            for (int r = 0; r < 4; r++)
                tsum[r] += __shfl_xor(tsum[r], off, 64);
        #pragma unroll
        for (int r = 0; r < 4; r++) {
            l_run[r] = l_run[r] * __expf(m_run[r] - tmax[r]) + tsum[r];
            m_run[r] = tmax[r];
        }
        __syncthreads();
    }

    float inv_l[4];
    #pragma unroll
    for (int r = 0; r < 4; r++) inv_l[r] = 1.f / l_run[r];

    f32x4 oacc[4] = {};

    // ---------- pass 2: P = exp(S-m)/l, write attn, O += P @ V ----------
    for (int kt = 0; kt < SEQ; kt += 64) {
        const unsigned short* ks = Kb + (size_t)(kt + sk) * DKH + sc0;
        *reinterpret_cast<bf16x8*>(&Ksm[sk][sc0])     = ld_bf8(ks);
        *reinterpret_cast<bf16x8*>(&Ksm[sk][sc0 + 8]) = ld_bf8(ks + 8);
        const unsigned short* vs = Vb + (size_t)(kt + sk) * DKH + sc0;
        #pragma unroll
        for (int j = 0; j < 16; j++) Vtsm[sc0 + j][sk] = vs[j];   // transpose in
        __syncthreads();

        f32x4 s[4];
        #pragma unroll
        for (int ni = 0; ni < 4; ni++) {
            bf16x8 k0f = ld_bf8(&Ksm[ni*16 + l15][lg*8]);
            bf16x8 k1f = ld_bf8(&Ksm[ni*16 + l15][32 + lg*8]);
            f32x4 zz = {};
            zz    = __builtin_amdgcn_mfma_f32_16x16x32_bf16(qf0, k0f, zz, 0, 0, 0);
            s[ni] = __builtin_amdgcn_mfma_f32_16x16x32_bf16(qf1, k1f, zz, 0, 0, 0);
        }
        #pragma unroll
        for (int ni = 0; ni < 4; ni++) {
            #pragma unroll
            for (int r = 0; r < 4; r++) {
                float p = __expf(s[ni][r] - m_run[r]) * inv_l[r];
                int qr = wv*16 + lg*4 + r;
                attn[((size_t)bh * SEQ + (size_t)(q0 + qr)) * SEQ + (size_t)(kt + ni*16 + l15)] = p;
                Psm[qr][ni*16 + l15] = f2bf(p);
            }
        }
        __syncthreads();

        bf16x8 pf0 = ld_bf8(&Psm[wv*16 + l15][lg*8]);
        bf16x8 pf1 = ld_bf8(&Psm[wv*16 + l15][32 + lg*8]);
        #pragma unroll
        for (int ni = 0; ni < 4; ni++) {
            bf16x8 v0f = ld_bf8(&Vtsm[ni*16 + l15][lg*8]);
            bf16x8 v1f = ld_bf8(&Vtsm[ni*16 + l15][32 + lg*8]);
            oacc[ni] = __builtin_amdgcn_mfma_f32_16x16x32_bf16(pf0, v0f, oacc[ni], 0, 0, 0);
            oacc[ni] = __builtin_amdgcn_mfma_f32_16x16x32_bf16(pf1, v1f, oacc[ni], 0, 0, 0);
        }
        __syncthreads();
    }

    // write O head-interleaved: Oh[b*2048+l][h*64+dv]
    #pragma unroll
    for (int ni = 0; ni < 4; ni++)
        #pragma unroll
        for (int r = 0; r < 4; r++) {
            int qr = wv*16 + lg*4 + r;
            int dv = ni*16 + l15;
            Oh[((size_t)(b*SEQ + q0 + qr))*DM + h*DKH + dv] = f2bf(oacc[ni][r]);
        }
}

// ---------------- output GEMM: out = Ohead(4096x1024 bf16) @ Wo + residual ----------------
__global__ __launch_bounds__(256) void out_kernel(
    const unsigned short* __restrict__ Oh, const float* __restrict__ Wo,
    const float* __restrict__ resid, float* __restrict__ out)
{
    __shared__ __align__(16) unsigned short Asm[64][40];
    __shared__ __align__(16) unsigned short Bsm[64][40];

    const int t = threadIdx.x;
    const int lane = t & 63, wv = t >> 6;
    const int wrow = wv >> 1, wcol = wv & 1;
    const int l15 = lane & 15, lg = lane >> 4;
    const int m0 = blockIdx.x * 64, n0 = blockIdx.y * 64;

    f32x4 acc[2][2] = {};

    const int ar = t >> 2, ac0 = (t & 3) * 8;
    const int br = t >> 3, bc0 = (t & 7) * 8;

    for (int k0 = 0; k0 < DM; k0 += 32) {
        *reinterpret_cast<bf16x8*>(&Asm[ar][ac0]) =
            ld_bf8(Oh + (size_t)(m0 + ar) * DM + (k0 + ac0));
        {
            const float* sb = Wo + (size_t)(k0 + br) * DM + (n0 + bc0);
            f32x4 b0 = *reinterpret_cast<const f32x4*>(sb);
            f32x4 b1 = *reinterpret_cast<const f32x4*>(sb + 4);
            #pragma unroll
            for (int j = 0; j < 4; j++) Bsm[bc0 + j][br]     = f2bf(b0[j]);
            #pragma unroll
            for (int j = 0; j < 4; j++) Bsm[bc0 + 4 + j][br] = f2bf(b1[j]);
        }
        __syncthreads();

        bf16x8 af0 = ld_bf8(&Asm[wrow*32 +      l15][lg*8]);
        bf16x8 af1 = ld_bf8(&Asm[wrow*32 + 16 + l15][lg*8]);
        bf16x8 bf0 = ld_bf8(&Bsm[wcol*32 +      l15][lg*8]);
        bf16x8 bf1 = ld_bf8(&Bsm[wcol*32 + 16 + l15][lg*8]);
        acc[0][0] = __builtin_amdgcn_mfma_f32_16x16x32_bf16(af0, bf0, acc[0][0], 0, 0, 0);
        acc[0][1] = __builtin_amdgcn_mfma_f32_16x16x32_bf16(af0, bf1, acc[0][1], 0, 0, 0);
        acc[1][0] = __builtin_amdgcn_mfma_f32_16x16x32_bf16(af1, bf0, acc[1][0], 0, 0, 0);
        acc[1][1] = __builtin_amdgcn_mfma_f32_16x16x32_bf16(af1, bf1, acc[1][1], 0, 0, 0);
        __syncthreads();
    }

    #pragma unroll
    for (int mi = 0; mi < 2; mi++)
        #pragma unroll
        for (int ni = 0; ni < 2; ni++)
            #pragma unroll
            for (int r = 0; r < 4; r++) {
                int gm = m0 + wrow*32 + mi*16 + lg*4 + r;
                int gn = n0 + wcol*32 + ni*16 + l15;
                size_t idx = (size_t)gm * DM + gn;
                out[idx] = acc[mi][ni][r] + resid[idx];
            }
}

extern "C" void kernel_launch(void* const* d_in, const int* in_sizes, int n_in,
                              void* d_out, int out_size, void* d_ws, size_t ws_size,
                              hipStream_t stream) {
    const float* q  = (const float*)d_in[0];
    const float* k  = (const float*)d_in[1];
    const float* v  = (const float*)d_in[2];
    const float* Wq = (const float*)d_in[3];
    const float* Wk = (const float*)d_in[4];
    const float* Wv = (const float*)d_in[5];
    const float* Wo = (const float*)d_in[6];

    float* out  = (float*)d_out;
    float* attn = out + (size_t)MTOT * DM;     // out is (2,2048,1024); attn follows

    unsigned short* Qh = (unsigned short*)d_ws;          // 4194304 bf16 each
    unsigned short* Kh = Qh + (size_t)4194304;
    unsigned short* Vh = Kh + (size_t)4194304;
    unsigned short* Oh = Vh + (size_t)4194304;           // total 32 MB of ws

    proj_kernel<<<dim3(64, 16, 3), 256, 0, stream>>>(q, k, v, Wq, Wk, Wv, Qh, Kh, Vh);
    attn_kernel<<<dim3(32, 32, 1), 256, 0, stream>>>(Qh, Kh, Vh, attn, Oh);
    out_kernel <<<dim3(64, 16, 1), 256, 0, stream>>>(Oh, Wo, q, out);
}